// Round 1
// baseline (265.867 us; speedup 1.0000x reference)
//
#include <hip/hip_runtime.h>

#define B_    2048
#define K_    32
#define D_    768
#define DICT_ 24576
#define C_    64

// K1: bdc[r] = dot(up_encoder_w[r,:], b_dec)   (one wave per row, float4)
__global__ void bdc_kernel(const float* __restrict__ up_enc,
                           const float* __restrict__ b_dec,
                           float* __restrict__ bdc) {
    int wave = threadIdx.x >> 6;
    int lane = threadIdx.x & 63;
    int row  = blockIdx.x * 4 + wave;
    const float4* rp = (const float4*)(up_enc + (size_t)row * D_);
    const float4* bp = (const float4*)b_dec;
    float acc = 0.f;
    #pragma unroll
    for (int i = 0; i < 3; ++i) {
        float4 a = rp[lane + 64 * i];
        float4 b = bp[lane + 64 * i];
        acc += a.x * b.x + a.y * b.y + a.z * b.z + a.w * b.w;
    }
    #pragma unroll
    for (int off = 32; off; off >>= 1) acc += __shfl_xor(acc, off);
    if (lane == 0) bdc[row] = acc;
}

// K2: one wave per (b,i). Unrolled readlane match-scan; matches are rare
// (~0.075/item), so pair-dots read up_dec columns directly (L3-resident)
// instead of paying a 151 MB transpose of the whole decoder matrix.
__global__ void main_kernel(const float* __restrict__ up_vals,
                            const float* __restrict__ up_dec,
                            const float* __restrict__ down_enc,
                            const float* __restrict__ up_enc,
                            const float* __restrict__ b_dec,
                            const int*   __restrict__ up_idx,
                            const int*   __restrict__ down_idx,
                            const int*   __restrict__ conn,
                            const float* __restrict__ bdc,  // may be null
                            float* __restrict__ out) {
    int wave = threadIdx.x >> 6;
    int lane = threadIdx.x & 63;
    int item = blockIdx.x * 4 + wave;      // item = b*32 + i
    int b    = item >> 5;

    int di = down_idx[item];
    int allowed = conn[(size_t)di * C_ + lane];   // lane c holds slot c (C_==64)
    bool valid = allowed >= 0;
    int   myup  = up_idx[b * K_ + (lane & 31)];
    float myval = up_vals[b * K_ + (lane & 31)];

    // Per-lane bitmask of which j's this slot matches. Compile-time j makes
    // __builtin_amdgcn_readlane an SGPR broadcast: ~3 VALU ops per j.
    unsigned jm = 0u;
    #pragma unroll
    for (int j = 0; j < K_; ++j) {
        int tgt = __builtin_amdgcn_readlane(myup, j);
        jm |= (valid && (allowed == tgt)) ? (1u << j) : 0u;
    }

    float acc = 0.f;
    if (__ballot(jm != 0u)) {              // wave-uniform; ~7% of items
        const float* drow = down_enc + (size_t)di * D_;
        #pragma unroll 1
        for (int j = 0; j < K_; ++j) {
            unsigned long long m = __ballot((jm >> j) & 1u);
            if (m != 0) {                  // wave-uniform branch
                float w   = (float)__popcll(m) * __shfl(myval, j);
                int   tgt = __shfl(myup, j);
                const float* colp = up_dec + tgt;
                float partial = 0.f;
                #pragma unroll
                for (int ii = 0; ii < 12; ++ii) {
                    int d = lane + 64 * ii;
                    partial += drow[d] * colp[(size_t)d * DICT_];
                }
                acc += w * partial;
            }
        }
    }

    if (!bdc) {  // inline bias fallback (no workspace)
        int ui = up_idx[item];
        const float4* rp = (const float4*)(up_enc + (size_t)ui * D_);
        const float4* bp = (const float4*)b_dec;
        #pragma unroll
        for (int ii = 0; ii < 3; ++ii) {
            float4 a  = rp[lane + 64 * ii];
            float4 bb = bp[lane + 64 * ii];
            acc += a.x * bb.x + a.y * bb.y + a.z * bb.z + a.w * bb.w;
        }
    }

    #pragma unroll
    for (int off = 32; off; off >>= 1) acc += __shfl_xor(acc, off);
    if (lane == 0) {
        float bias = bdc ? bdc[up_idx[item]] : 0.f;
        out[item] = acc + bias;
    }
}

extern "C" void kernel_launch(void* const* d_in, const int* in_sizes, int n_in,
                              void* d_out, int out_size, void* d_ws, size_t ws_size,
                              hipStream_t stream) {
    (void)in_sizes; (void)n_in; (void)out_size;
    const float* up_vals  = (const float*)d_in[0];
    const float* up_dec   = (const float*)d_in[1];
    const float* down_enc = (const float*)d_in[2];
    const float* up_enc   = (const float*)d_in[3];
    const float* b_dec    = (const float*)d_in[4];
    const int*   up_idx   = (const int*)d_in[5];
    const int*   down_idx = (const int*)d_in[6];
    const int*   conn     = (const int*)d_in[7];
    float* out = (float*)d_out;

    size_t bdc_bytes = (size_t)DICT_ * sizeof(float);
    float* bdc = (ws_size >= bdc_bytes) ? (float*)d_ws : nullptr;

    if (bdc) {
        bdc_kernel<<<DICT_ / 4, 256, 0, stream>>>(up_enc, b_dec, bdc);
    }
    main_kernel<<<(B_ * K_) / 4, 256, 0, stream>>>(up_vals, up_dec, down_enc,
                                                   up_enc, b_dec, up_idx,
                                                   down_idx, conn, bdc, out);
}

// Round 2
// 256.919 us; speedup vs baseline: 1.0348x; 1.0348x over previous
//
#include <hip/hip_runtime.h>

#define B_    2048
#define K_    32
#define D_    768
#define DICT_ 24576
#define C_    64

// K0: transpose up_decoder_w [D][DICT] -> T [DICT][D].
// 64x64 tiles, float4 on both global sides (1 KiB per wave instruction).
// LDS [64][65]: both write and read phases are 2-way bank aliased (free on CDNA4).
__global__ __launch_bounds__(256) void transpose_kernel(const float* __restrict__ A,
                                                        float* __restrict__ T) {
    __shared__ float tile[64][65];
    int fx = threadIdx.x & 15;        // float4 index within a 64-wide row
    int fy = threadIdx.x >> 4;        // 0..15
    int x0 = blockIdx.x * 64;         // dict origin
    int y0 = blockIdx.y * 64;         // d origin
    #pragma unroll
    for (int k = 0; k < 4; ++k) {
        int d = y0 + fy + 16 * k;
        float4 v = *(const float4*)(A + (size_t)d * DICT_ + x0 + 4 * fx);
        tile[4 * fx + 0][fy + 16 * k] = v.x;
        tile[4 * fx + 1][fy + 16 * k] = v.y;
        tile[4 * fx + 2][fy + 16 * k] = v.z;
        tile[4 * fx + 3][fy + 16 * k] = v.w;
    }
    __syncthreads();
    #pragma unroll
    for (int k = 0; k < 4; ++k) {
        int row = fy + 16 * k;        // dict-local
        float4 v;
        v.x = tile[row][4 * fx + 0];
        v.y = tile[row][4 * fx + 1];
        v.z = tile[row][4 * fx + 2];
        v.w = tile[row][4 * fx + 3];
        *(float4*)(T + (size_t)(x0 + row) * D_ + y0 + 4 * fx) = v;
    }
}

// K1: bdc[r] = dot(up_encoder_w[r,:], b_dec)   (one wave per row, float4)
__global__ void bdc_kernel(const float* __restrict__ up_enc,
                           const float* __restrict__ b_dec,
                           float* __restrict__ bdc) {
    int wave = threadIdx.x >> 6;
    int lane = threadIdx.x & 63;
    int row  = blockIdx.x * 4 + wave;
    const float4* rp = (const float4*)(up_enc + (size_t)row * D_);
    const float4* bp = (const float4*)b_dec;
    float acc = 0.f;
    #pragma unroll
    for (int i = 0; i < 3; ++i) {
        float4 a = rp[lane + 64 * i];
        float4 b = bp[lane + 64 * i];
        acc += a.x * b.x + a.y * b.y + a.z * b.z + a.w * b.w;
    }
    #pragma unroll
    for (int off = 32; off; off >>= 1) acc += __shfl_xor(acc, off);
    if (lane == 0) bdc[row] = acc;
}

// K2: one wave per (b,i). Cheap unrolled readlane match-scan (matches ~0.075/item);
// rare pair-dots read T rows coalesced (float4) instead of up_dec columns
// (scattered columns cost 16x line over-fetch: 248 MB HBM, measured round 1).
__global__ void main_kernel(const float* __restrict__ up_vals,
                            const float* __restrict__ up_dec,
                            const float* __restrict__ down_enc,
                            const float* __restrict__ up_enc,
                            const float* __restrict__ b_dec,
                            const int*   __restrict__ up_idx,
                            const int*   __restrict__ down_idx,
                            const int*   __restrict__ conn,
                            const float* __restrict__ T,    // may be null
                            const float* __restrict__ bdc,  // may be null
                            float* __restrict__ out) {
    int wave = threadIdx.x >> 6;
    int lane = threadIdx.x & 63;
    int item = blockIdx.x * 4 + wave;      // item = b*32 + i
    int b    = item >> 5;

    int di = down_idx[item];
    int allowed = conn[(size_t)di * C_ + lane];   // lane c holds slot c (C_==64)
    bool valid = allowed >= 0;
    int   myup  = up_idx[b * K_ + (lane & 31)];
    float myval = up_vals[b * K_ + (lane & 31)];

    // Per-lane bitmask of which j's this slot matches. Compile-time j makes
    // __builtin_amdgcn_readlane an SGPR broadcast: ~3 VALU ops per j.
    unsigned jm = 0u;
    #pragma unroll
    for (int j = 0; j < K_; ++j) {
        int tgt = __builtin_amdgcn_readlane(myup, j);
        jm |= (valid && (allowed == tgt)) ? (1u << j) : 0u;
    }

    float acc = 0.f;
    if (__ballot(jm != 0u)) {              // wave-uniform; ~7% of items
        const float* drow = down_enc + (size_t)di * D_;
        #pragma unroll 1
        for (int j = 0; j < K_; ++j) {
            unsigned long long m = __ballot((jm >> j) & 1u);
            if (m != 0) {                  // wave-uniform branch
                float w   = (float)__popcll(m) * __shfl(myval, j);
                int   tgt = __shfl(myup, j);
                float partial = 0.f;
                if (T) {
                    const float4* cp = (const float4*)(T + (size_t)tgt * D_);
                    const float4* dp = (const float4*)drow;
                    #pragma unroll
                    for (int ii = 0; ii < 3; ++ii) {
                        float4 c = cp[lane + 64 * ii];
                        float4 d = dp[lane + 64 * ii];
                        partial += c.x * d.x + c.y * d.y + c.z * d.z + c.w * d.w;
                    }
                } else {
                    const float* colp = up_dec + tgt;
                    #pragma unroll
                    for (int ii = 0; ii < 12; ++ii) {
                        int d = lane + 64 * ii;
                        partial += drow[d] * colp[(size_t)d * DICT_];
                    }
                }
                acc += w * partial;
            }
        }
    }

    if (!bdc) {  // inline bias fallback (no workspace)
        int ui = up_idx[item];
        const float4* rp = (const float4*)(up_enc + (size_t)ui * D_);
        const float4* bp = (const float4*)b_dec;
        #pragma unroll
        for (int ii = 0; ii < 3; ++ii) {
            float4 a  = rp[lane + 64 * ii];
            float4 bb = bp[lane + 64 * ii];
            acc += a.x * bb.x + a.y * bb.y + a.z * bb.z + a.w * bb.w;
        }
    }

    #pragma unroll
    for (int off = 32; off; off >>= 1) acc += __shfl_xor(acc, off);
    if (lane == 0) {
        float bias = bdc ? bdc[up_idx[item]] : 0.f;
        out[item] = acc + bias;
    }
}

extern "C" void kernel_launch(void* const* d_in, const int* in_sizes, int n_in,
                              void* d_out, int out_size, void* d_ws, size_t ws_size,
                              hipStream_t stream) {
    (void)in_sizes; (void)n_in; (void)out_size;
    const float* up_vals  = (const float*)d_in[0];
    const float* up_dec   = (const float*)d_in[1];
    const float* down_enc = (const float*)d_in[2];
    const float* up_enc   = (const float*)d_in[3];
    const float* b_dec    = (const float*)d_in[4];
    const int*   up_idx   = (const int*)d_in[5];
    const int*   down_idx = (const int*)d_in[6];
    const int*   conn     = (const int*)d_in[7];
    float* out = (float*)d_out;

    size_t bdc_bytes = (size_t)DICT_ * sizeof(float);
    size_t T_bytes   = (size_t)DICT_ * D_ * sizeof(float);
    float* bdc = (ws_size >= bdc_bytes) ? (float*)d_ws : nullptr;
    float* T   = (ws_size >= bdc_bytes + T_bytes) ? (float*)d_ws + DICT_ : nullptr;

    if (T) {
        dim3 grid(DICT_ / 64, D_ / 64);
        transpose_kernel<<<grid, 256, 0, stream>>>(up_dec, T);
    }
    if (bdc) {
        bdc_kernel<<<DICT_ / 4, 256, 0, stream>>>(up_enc, b_dec, bdc);
    }
    main_kernel<<<(B_ * K_) / 4, 256, 0, stream>>>(up_vals, up_dec, down_enc, up_enc,
                                                   b_dec, up_idx, down_idx, conn,
                                                   T, bdc, out);
}